// Round 2
// baseline (1934.367 us; speedup 1.0000x reference)
//
#include <hip/hip_runtime.h>

#define B_ 16
#define T_ 65536
#define H_ 64
#define DEPTH_ 4
#define CHUNK 64
#define NCH (T_ / CHUNK)   // 1024 chunks per sequence
#define NCH_LOG 10

typedef _Float16 f16;
typedef f16 f16x8 __attribute__((ext_vector_type(8)));
typedef float f32x4 __attribute__((ext_vector_type(4)));
typedef unsigned u32x4 __attribute__((ext_vector_type(4)));

#define MFMA(a, b, c) __builtin_amdgcn_mfma_f32_16x16x32_f16(a, b, c, 0, 0, 0)
// swizzled word index into hpk: row t (0..63), word k (0..63)
#define SWZ(t, k) ((t) * 64 + ((k) ^ (((t) & 7) << 2)))

union U4F8 { u32x4 u; f16x8 h; };

__device__ __forceinline__ f16x8 ldfrag(const f16* p) { return *(const f16x8*)p; }

// ---------- prep: pack weights to f16 hi/lo, decay tables, scalars ----------
// sc per layer (stride 320 floats): [0]=a, [64]=Dv, [128]=bw(=g*Bm.Win), [192]=Dv*Win, [256]=Win
__global__ __launch_bounds__(256)
void prep(const float* __restrict__ Win, const float* __restrict__ nu,
          const float* __restrict__ ga, const float* __restrict__ Bm,
          const float* __restrict__ Cm, const float* __restrict__ Dv,
          const float* __restrict__ Wl,
          f16* __restrict__ BmH, f16* __restrict__ BmL,
          f16* __restrict__ CmH, f16* __restrict__ CmL,
          f16* __restrict__ WlH, float* __restrict__ atab, float* __restrict__ sc)
{
    const int tid = threadIdx.x;
    for (int l = 0; l < DEPTH_; ++l) {
        for (int idx = tid; idx < 4096; idx += 256) {
            int n = idx >> 6;
            float g = expf(ga[l * 64 + n]);
            float v = Bm[l * 4096 + idx] * g;
            f16 h = (f16)v;
            BmH[l * 4096 + idx] = h;
            BmL[l * 4096 + idx] = (f16)(v - (float)h);
            float cv = Cm[l * 4096 + idx];
            h = (f16)cv;
            CmH[l * 4096 + idx] = h;
            CmL[l * 4096 + idx] = (f16)(cv - (float)h);
            WlH[l * 4096 + idx] = (f16)Wl[l * 4096 + idx];
        }
        if (tid < 64) {
            int n = tid;
            float ex = expf(nu[l * 64 + n]);
            float a = expf(-ex);
            float g = expf(ga[l * 64 + n]);
            sc[l * 320 + n] = a;
            sc[l * 320 + 64 + n] = Dv[l * 64 + n];
            float bw = 0.f;
            for (int h2 = 0; h2 < 64; ++h2) bw += Bm[l * 4096 + n * 64 + h2] * Win[h2];
            sc[l * 320 + 128 + n] = bw * g;
            sc[l * 320 + 192 + n] = Dv[l * 64 + n] * Win[n];
            sc[l * 320 + 256 + n] = Win[n];
        }
        for (int idx = tid; idx < 8192; idx += 256) {
            int n = idx >> 7, j = idx & 127;
            float ex = expf(nu[l * 64 + n]);
            atab[l * 8192 + idx] = expf(-ex * (float)j);
        }
    }
}

// ---------- raw carry for layer 0 (u_t = x_t*Win, rank-1) ----------
__global__ __launch_bounds__(64)
void carry_x(const float* __restrict__ x, const float* __restrict__ sc0,
             float* __restrict__ carry)
{
    const int blk = blockIdx.x;
    const int b = blk >> NCH_LOG, c = blk & (NCH - 1);
    const int n = threadIdx.x;
    const float a  = sc0[n];
    const float bw = sc0[128 + n];
    __shared__ float xs[64];
    const float* xp = x + (size_t)b * T_ + c * CHUNK;
    float s = 0.f;
    for (int bb = 0; bb < CHUNK / 64 + (CHUNK < 64 ? 1 : 0); ++bb) {
        __syncthreads();
        xs[n] = xp[bb * 64 + n];
        __syncthreads();
        #pragma unroll
        for (int tt = 0; tt < (CHUNK < 64 ? CHUNK : 64); ++tt) s = a * s + bw * xs[tt];
    }
    carry[((size_t)b * NCH + c) * 64 + n] = s;
}

// ---------- in-place exclusive decay-scan of per-chunk carries ----------
__global__ __launch_bounds__(256)
void scan_carry(const float* __restrict__ nu_log, float* __restrict__ carry)
{
    const int b = blockIdx.x;
    const int tid = threadIdx.x;
    const int n = tid & 63, q = tid >> 6;
    const float ex = expf(nu_log[n]);
    const float aL = expf(-ex * (float)CHUNK);
    float* cp = carry + (size_t)b * NCH * 64 + n;
    __shared__ float part[4][64];

    const int SEG = NCH / 4;
    const int base = q * SEG;
    float p = 0.f;
    #pragma unroll 4
    for (int i = 0; i < SEG; ++i) {
        float v = cp[(size_t)(base + i) * 64];
        cp[(size_t)(base + i) * 64] = p;
        p = aL * p + v;
    }
    part[q][n] = p;
    __syncthreads();
    if (q > 0) {
        const float aLS = expf(-ex * (float)(CHUNK * SEG));
        float inc = 0.f;
        for (int qq = 0; qq < q; ++qq) inc = inc * aLS + part[qq][n];
        float qv = inc;
        #pragma unroll 4
        for (int i = 0; i < SEG; ++i) {
            cp[(size_t)(base + i) * 64] += qv;
            qv *= aL;
        }
    }
}

struct LPrep {
    const f16 *BmH, *BmL, *CmH, *CmL, *WlH;  // this layer (gamma folded into Bm)
    const float *av, *dvv, *bw, *dwin, *win; // this-layer scalars
    const f16 *BmHn, *BmLn;                  // next-layer Bm (gamma folded)
    const float *atabn;                      // next-layer decay table a^j
    const float *blin, *Wout;
};

// ---------- fused chunk kernel ----------
// 256 threads = 4 waves, each wave owns 16 rows (t = 16*w + 4*lq + r), CHUNK=64.
// LDS = 16K hpk + 1K swv + 1K red = 18432 B -> 8 blocks/CU * 4 waves = 32 waves/CU.
// (Round-1 lesson: 512thr/__launch_bounds__(512,8) forced VGPR 64->32 with mass
//  scratch spills, +660 MB HBM/dispatch. Here the 16-row state fits 64 VGPRs.)
template<int IN_X, int OUT_FINAL>
__global__ __launch_bounds__(256, 8)
void lru_fused(const float* __restrict__ x, f16* __restrict__ ubuf,
               LPrep P, float* __restrict__ carry, float* __restrict__ out)
{
    const int blk = blockIdx.x;
    const int b = blk >> NCH_LOG, c = blk & (NCH - 1);
    const int t0 = c * CHUNK;
    const int tid = threadIdx.x;
    const int w = tid >> 6, lane = tid & 63;
    const int l15 = lane & 15, lq = lane >> 4;

    __shared__ float hpk[CHUNK * 64];   // 16 KB fp32: holds h_prev -> th -> staged o
    __shared__ float swv[4][64];
    __shared__ float red[4][64];

    f16* ug = ubuf + ((size_t)b * T_ + t0) * 64;
    const float* xg = x + (size_t)b * T_ + t0;

    // u A-frag (nontemporal, read-once): own 16-row block
    f16x8 ahu[2];
    if (!IN_X) {
        const f16* p = ug + (size_t)(16 * w + l15) * 64;
        U4F8 r0, r1;
        r0.u = __builtin_nontemporal_load((const u32x4*)(p + lq * 8));
        r1.u = __builtin_nontemporal_load((const u32x4*)(p + 32 + lq * 8));
        ahu[0] = r0.h;
        ahu[1] = r1.h;
    }

    float av4[4];
    #pragma unroll
    for (int nt = 0; nt < 4; ++nt) av4[nt] = P.av[nt * 16 + l15];

    float xv[4];
    if (IN_X) {
        #pragma unroll
        for (int r = 0; r < 4; ++r) xv[r] = xg[16 * w + 4 * lq + r];
    }

    // ---- P1: Bu in registers (MFMA C-layout: row t=16w+lq*4+r, col n=nt*16+l15) ----
    f32x4 acc[4];
    if (IN_X) {
        #pragma unroll
        for (int nt = 0; nt < 4; ++nt) {
            float bwn = P.bw[nt * 16 + l15];
            #pragma unroll
            for (int r = 0; r < 4; ++r) acc[nt][r] = xv[r] * bwn;
        }
    } else {
        #pragma unroll
        for (int nt = 0; nt < 4; ++nt) {
            int n = nt * 16 + l15;
            f16x8 bh0 = ldfrag(P.BmH + n * 64 + lq * 8);
            f16x8 bh1 = ldfrag(P.BmH + n * 64 + 32 + lq * 8);
            f16x8 bl0 = ldfrag(P.BmL + n * 64 + lq * 8);
            f16x8 bl1 = ldfrag(P.BmL + n * 64 + 32 + lq * 8);
            f32x4 a4v = {0.f, 0.f, 0.f, 0.f};
            a4v = MFMA(ahu[0], bh0, a4v);
            a4v = MFMA(ahu[0], bl0, a4v);
            a4v = MFMA(ahu[1], bh1, a4v);
            a4v = MFMA(ahu[1], bl1, a4v);
            acc[nt] = a4v;
        }
    }

    // ---- P2: register scan with decayed shfl (per n, over own 16 rows) ----
    float Wb[4];
    #pragma unroll
    for (int nt = 0; nt < 4; ++nt) {
        float a = av4[nt], a2 = a * a, a4 = a2 * a2, a8 = a4 * a4;
        f32x4 xs = acc[nt];
        float L0 = xs[0];
        float L1 = a * L0 + xs[1];
        float L2 = a * L1 + xs[2];
        float Cv = a * L2 + xs[3];
        float u1 = __shfl_up(Cv, 16);
        float t1 = Cv + ((lq >= 1) ? a4 * u1 : 0.f);
        float u2 = __shfl_up(t1, 32);
        float Pv = t1 + ((lq >= 2) ? a8 * u2 : 0.f);
        float E = __shfl_up(Pv, 16);
        Wb[nt] = (lq == 0) ? 0.f : E;
        if (lq == 3) swv[w][nt * 16 + l15] = Pv;   // inclusive 16-row wave total
    }
    __syncthreads();                       // barrier 1

    // ---- inc + h_prev writes (fp32, own 16 rows) ----
    #pragma unroll
    for (int nt = 0; nt < 4; ++nt) {
        int n = nt * 16 + l15;
        float a = av4[nt], a2 = a * a, a4 = a2 * a2, a8 = a4 * a4, a16 = a8 * a8;
        float inc = carry[((size_t)b * NCH + c) * 64 + n];
        for (int ww = 0; ww < w; ++ww) inc = inc * a16 + swv[ww][n];
        float a4lq = 1.f;
        if (lq & 1) a4lq *= a4;
        if (lq & 2) a4lq *= a8;
        float s = Wb[nt] + a4lq * inc;
        #pragma unroll
        for (int r = 0; r < 4; ++r) {
            int t = 16 * w + 4 * lq + r;
            hpk[SWZ(t, n)] = s;           // h_{t-1}
            s = a * s + acc[nt][r];
        }
    }
    // no barrier: all subsequent hpk traffic is own-wave rows

    // ---- P3: y = C.h_prev + Dv*u, tanh -> th (fp32, overwrite h) ----
    {
        const int trow = 16 * w + l15, sw = (trow & 7) << 2;
        const float* hw = hpk + trow * 64;
        f16x8 ah[2], al[2];
        #pragma unroll
        for (int kk = 0; kk < 2; ++kk) {
            int kb = kk * 32 + lq * 8;
            float4 v0 = *(const float4*)(hw + (kb ^ sw));
            float4 v1 = *(const float4*)(hw + ((kb + 4) ^ sw));
            float vv[8] = {v0.x, v0.y, v0.z, v0.w, v1.x, v1.y, v1.z, v1.w};
            #pragma unroll
            for (int i = 0; i < 8; ++i) {
                f16 h = (f16)vv[i];
                ah[kk][i] = h;
                al[kk][i] = (f16)(vv[i] - (float)h);
            }
        }
        #pragma unroll
        for (int nt = 0; nt < 4; ++nt) {
            int n = nt * 16 + l15;
            f16x8 ch0 = ldfrag(P.CmH + n * 64 + lq * 8);
            f16x8 ch1 = ldfrag(P.CmH + n * 64 + 32 + lq * 8);
            f16x8 cl0 = ldfrag(P.CmL + n * 64 + lq * 8);
            f16x8 cl1 = ldfrag(P.CmL + n * 64 + 32 + lq * 8);
            f32x4 a4v = {0.f, 0.f, 0.f, 0.f};
            a4v = MFMA(ah[0], ch0, a4v);
            a4v = MFMA(al[0], ch0, a4v);
            a4v = MFMA(ah[0], cl0, a4v);
            a4v = MFMA(ah[1], ch1, a4v);
            a4v = MFMA(al[1], ch1, a4v);
            a4v = MFMA(ah[1], cl1, a4v);
            if (!IN_X) {
                float dv = P.dvv[n];
                f16 dh = (f16)dv, dl = (f16)(dv - (float)dh);
                f16x8 dfh, dfl;
                #pragma unroll
                for (int i2 = 0; i2 < 8; ++i2) { dfh[i2] = (f16)0.f; dfl[i2] = (f16)0.f; }
                int e = ((nt & 1) * 16 + l15) - lq * 8;
                if (e >= 0 && e < 8) { dfh[e] = dh; dfl[e] = dl; }
                a4v = MFMA(ahu[nt >> 1], dfh, a4v);
                a4v = MFMA(ahu[nt >> 1], dfl, a4v);
            }
            float dwin = IN_X ? P.dwin[n] : 0.f;
            #pragma unroll
            for (int r = 0; r < 4; ++r) {
                int t = 16 * w + lq * 4 + r;
                float y = a4v[r];
                if (IN_X) y += xv[r] * dwin;
                hpk[SWZ(t, n)] = y * rsqrtf(1.f + y * y);
            }
        }
    }

    // ---- P4: o = Wlin.th + blin + u; stage as f16 (low 32 words) or final reduce ----
    f16* stg = (f16*)hpk;
    {
        const int trow = 16 * w + l15, sw = (trow & 7) << 2;
        const float* hw = hpk + trow * 64;
        f16x8 t0f, t1f;
        #pragma unroll
        for (int kk = 0; kk < 2; ++kk) {
            int kb = kk * 32 + lq * 8;
            float4 v0 = *(const float4*)(hw + (kb ^ sw));
            float4 v1 = *(const float4*)(hw + ((kb + 4) ^ sw));
            float vv[8] = {v0.x, v0.y, v0.z, v0.w, v1.x, v1.y, v1.z, v1.w};
            #pragma unroll
            for (int i = 0; i < 8; ++i) {
                if (kk == 0) t0f[i] = (f16)vv[i]; else t1f[i] = (f16)vv[i];
            }
        }
        float val[4] = {0.f, 0.f, 0.f, 0.f};
        #pragma unroll
        for (int nt = 0; nt < 4; ++nt) {
            int n = nt * 16 + l15;
            f16x8 w0f = ldfrag(P.WlH + n * 64 + lq * 8);
            f16x8 w1f = ldfrag(P.WlH + n * 64 + 32 + lq * 8);
            f32x4 a4v = {0.f, 0.f, 0.f, 0.f};
            a4v = MFMA(t0f, w0f, a4v);
            a4v = MFMA(t1f, w1f, a4v);
            if (!IN_X) {
                f16x8 ifr;
                #pragma unroll
                for (int i2 = 0; i2 < 8; ++i2) ifr[i2] = (f16)0.f;
                int e = ((nt & 1) * 16 + l15) - lq * 8;
                if (e >= 0 && e < 8) ifr[e] = (f16)1.f;
                a4v = MFMA(ahu[nt >> 1], ifr, a4v);
            }
            float blj = P.blin[n];
            float wij = IN_X ? P.win[n] : 0.f;
            float woj = OUT_FINAL ? P.Wout[n] : 0.f;
            #pragma unroll
            for (int r = 0; r < 4; ++r) {
                int t = 16 * w + lq * 4 + r;
                float o = a4v[r] + blj;
                if (IN_X) o += xv[r] * wij;
                if (OUT_FINAL) {
                    val[r] += o * woj;
                } else {
                    int g = n >> 1;
                    int word = t * 64 + (((g & ~3) ^ ((t & 7) << 2)) | (g & 3));
                    stg[word * 2 + (n & 1)] = (f16)o;
                }
            }
        }
        if (OUT_FINAL) {
            #pragma unroll
            for (int r = 0; r < 4; ++r) {
                float p = val[r];
                p += __shfl_xor(p, 1);
                p += __shfl_xor(p, 2);
                p += __shfl_xor(p, 4);
                p += __shfl_xor(p, 8);
                if (l15 == 0) out[(size_t)b * T_ + t0 + 16 * w + lq * 4 + r] = p;
            }
        }
    }

    if (!OUT_FINAL) {
        // ---- coalesced nontemporal store of own 16 rows ----
        #pragma unroll
        for (int i = 0; i < 2; ++i) {
            int row = 16 * w + i * 8 + (lane >> 3);
            int gg = 4 * (lane & 7);
            int word = row * 64 + (gg ^ ((row & 7) << 2));
            u32x4 cv = *(const u32x4*)(hpk + word);
            __builtin_nontemporal_store(cv, (u32x4*)(ug + (size_t)row * 64 + 8 * (lane & 7)));
        }

        // ---- next-layer raw-carry GEMM from staged tile ----
        float partial[4] = {0.f, 0.f, 0.f, 0.f};
        {
            const int arow = 16 * w + l15, msk = (arow & 7) << 2;
            U4F8 av0, av1;
            av0.u = *(const u32x4*)(hpk + arow * 64 + ((4 * lq) ^ msk));
            av1.u = *(const u32x4*)(hpk + arow * 64 + ((16 + 4 * lq) ^ msk));
            #pragma unroll
            for (int nt = 0; nt < 4; ++nt) {
                int n = nt * 16 + l15;
                f16x8 bh0 = ldfrag(P.BmHn + n * 64 + lq * 8);
                f16x8 bh1 = ldfrag(P.BmHn + n * 64 + 32 + lq * 8);
                f16x8 bl0 = ldfrag(P.BmLn + n * 64 + lq * 8);
                f16x8 bl1 = ldfrag(P.BmLn + n * 64 + 32 + lq * 8);
                f32x4 a4v = {0.f, 0.f, 0.f, 0.f};
                a4v = MFMA(av0.h, bh0, a4v);
                a4v = MFMA(av0.h, bl0, a4v);
                a4v = MFMA(av1.h, bh1, a4v);
                a4v = MFMA(av1.h, bl1, a4v);
                // decay weight a^(CHUNK-1-t), t = 16w+4lq+r
                float4 dp = *(const float4*)(P.atabn + n * 128 + (CHUNK - 4) - w * 16 - lq * 4);
                partial[nt] += a4v[0] * dp.w + a4v[1] * dp.z + a4v[2] * dp.y + a4v[3] * dp.x;
            }
        }
        #pragma unroll
        for (int nt = 0; nt < 4; ++nt) {
            float v = partial[nt];
            v += __shfl_xor(v, 16);
            v += __shfl_xor(v, 32);
            if (lq == 0) red[w][nt * 16 + l15] = v;
        }
        __syncthreads();                   // barrier 2
        if (w == 0)
            carry[((size_t)b * NCH + c) * 64 + lane] =
                red[0][lane] + red[1][lane] + red[2][lane] + red[3][lane];
    }
}

// ---------- host ----------
extern "C" void kernel_launch(void* const* d_in, const int* in_sizes, int n_in,
                              void* d_out, int out_size, void* d_ws, size_t ws_size,
                              hipStream_t stream)
{
    const float* x   = (const float*)d_in[0];
    const float* Win = (const float*)d_in[1];
    const float* nu  = (const float*)d_in[2];
    const float* ga  = (const float*)d_in[3];
    const float* Bm  = (const float*)d_in[4];
    const float* Cm  = (const float*)d_in[5];
    const float* Dv  = (const float*)d_in[6];
    const float* Wl  = (const float*)d_in[7];
    const float* bl  = (const float*)d_in[8];
    const float* Wo  = (const float*)d_in[9];
    float* out = (float*)d_out;

    char* p = (char*)d_ws;
    f16* ubuf = (f16*)p;            p += (size_t)B_ * T_ * 64 * sizeof(f16);
    float* carry = (float*)p;       p += (size_t)B_ * NCH * 64 * sizeof(float);
    f16* wBmH = (f16*)p;            p += 4 * 4096 * sizeof(f16);
    f16* wBmL = (f16*)p;            p += 4 * 4096 * sizeof(f16);
    f16* wCmH = (f16*)p;            p += 4 * 4096 * sizeof(f16);
    f16* wCmL = (f16*)p;            p += 4 * 4096 * sizeof(f16);
    f16* wWlH = (f16*)p;            p += 4 * 4096 * sizeof(f16);
    float* atab = (float*)p;        p += 4 * 8192 * sizeof(float);
    float* sc = (float*)p;          p += 4 * 320 * sizeof(float);

    dim3 grid(B_ * NCH), blk256(256), blk64(64), gscan(B_);

    prep<<<1, blk256, 0, stream>>>(Win, nu, ga, Bm, Cm, Dv, Wl,
                                   wBmH, wBmL, wCmH, wCmL, wWlH, atab, sc);
    carry_x<<<grid, blk64, 0, stream>>>(x, sc, carry);

    for (int l = 0; l < DEPTH_; ++l) {
        int ln = (l + 1 < DEPTH_) ? l + 1 : l;
        scan_carry<<<gscan, blk256, 0, stream>>>(nu + l * 64, carry);
        LPrep Pr;
        Pr.BmH = wBmH + l * 4096;  Pr.BmL = wBmL + l * 4096;
        Pr.CmH = wCmH + l * 4096;  Pr.CmL = wCmL + l * 4096;
        Pr.WlH = wWlH + l * 4096;
        Pr.av = sc + l * 320;       Pr.dvv = sc + l * 320 + 64;
        Pr.bw = sc + l * 320 + 128; Pr.dwin = sc + l * 320 + 192;
        Pr.win = sc + l * 320 + 256;
        Pr.BmHn = wBmH + ln * 4096; Pr.BmLn = wBmL + ln * 4096;
        Pr.atabn = atab + ln * 8192;
        Pr.blin = bl + l * 64; Pr.Wout = Wo;
        if (l == 0)
            lru_fused<1, 0><<<grid, blk256, 0, stream>>>(x, ubuf, Pr, carry, out);
        else if (l == DEPTH_ - 1)
            lru_fused<0, 1><<<grid, blk256, 0, stream>>>(x, ubuf, Pr, carry, out);
        else
            lru_fused<0, 0><<<grid, blk256, 0, stream>>>(x, ubuf, Pr, carry, out);
    }
}

// Round 3
// 1827.896 us; speedup vs baseline: 1.0582x; 1.0582x over previous
//
#include <hip/hip_runtime.h>

#define B_ 16
#define T_ 65536
#define H_ 64
#define DEPTH_ 4
#define CHUNK 64
#define NCH (T_ / CHUNK)   // 1024 chunks per sequence
#define NCH_LOG 10

typedef _Float16 f16;
typedef f16 f16x8 __attribute__((ext_vector_type(8)));
typedef float f32x4 __attribute__((ext_vector_type(4)));
typedef unsigned u32x4 __attribute__((ext_vector_type(4)));

#define MFMA(a, b, c) __builtin_amdgcn_mfma_f32_16x16x32_f16(a, b, c, 0, 0, 0)
// swizzled word index into hpk: row t (0..63), word k (0..63)
#define SWZ(t, k) ((t) * 64 + ((k) ^ (((t) & 7) << 2)))

union U4F8 { u32x4 u; f16x8 h; };

__device__ __forceinline__ f16x8 ldfrag(const f16* p) { return *(const f16x8*)p; }

// ---------- prep: pack weights to f16 hi/lo, decay tables, scalars ----------
// sc per layer (stride 320 floats): [0]=a, [64]=Dv, [128]=bw(=g*Bm.Win), [192]=Dv*Win, [256]=Win
__global__ __launch_bounds__(256)
void prep(const float* __restrict__ Win, const float* __restrict__ nu,
          const float* __restrict__ ga, const float* __restrict__ Bm,
          const float* __restrict__ Cm, const float* __restrict__ Dv,
          const float* __restrict__ Wl,
          f16* __restrict__ BmH, f16* __restrict__ BmL,
          f16* __restrict__ CmH, f16* __restrict__ CmL,
          f16* __restrict__ WlH, float* __restrict__ atab, float* __restrict__ sc)
{
    const int tid = threadIdx.x;
    for (int l = 0; l < DEPTH_; ++l) {
        for (int idx = tid; idx < 4096; idx += 256) {
            int n = idx >> 6;
            float g = expf(ga[l * 64 + n]);
            float v = Bm[l * 4096 + idx] * g;
            f16 h = (f16)v;
            BmH[l * 4096 + idx] = h;
            BmL[l * 4096 + idx] = (f16)(v - (float)h);
            float cv = Cm[l * 4096 + idx];
            h = (f16)cv;
            CmH[l * 4096 + idx] = h;
            CmL[l * 4096 + idx] = (f16)(cv - (float)h);
            WlH[l * 4096 + idx] = (f16)Wl[l * 4096 + idx];
        }
        if (tid < 64) {
            int n = tid;
            float ex = expf(nu[l * 64 + n]);
            float a = expf(-ex);
            float g = expf(ga[l * 64 + n]);
            sc[l * 320 + n] = a;
            sc[l * 320 + 64 + n] = Dv[l * 64 + n];
            float bw = 0.f;
            for (int h2 = 0; h2 < 64; ++h2) bw += Bm[l * 4096 + n * 64 + h2] * Win[h2];
            sc[l * 320 + 128 + n] = bw * g;
            sc[l * 320 + 192 + n] = Dv[l * 64 + n] * Win[n];
            sc[l * 320 + 256 + n] = Win[n];
        }
        for (int idx = tid; idx < 8192; idx += 256) {
            int n = idx >> 7, j = idx & 127;
            float ex = expf(nu[l * 64 + n]);
            atab[l * 8192 + idx] = expf(-ex * (float)j);
        }
    }
}

// ---------- raw carry for layer 0 (u_t = x_t*Win, rank-1) ----------
__global__ __launch_bounds__(64)
void carry_x(const float* __restrict__ x, const float* __restrict__ sc0,
             float* __restrict__ carry)
{
    const int blk = blockIdx.x;
    const int b = blk >> NCH_LOG, c = blk & (NCH - 1);
    const int n = threadIdx.x;
    const float a  = sc0[n];
    const float bw = sc0[128 + n];
    __shared__ float xs[64];
    const float* xp = x + (size_t)b * T_ + c * CHUNK;
    float s = 0.f;
    for (int bb = 0; bb < CHUNK / 64 + (CHUNK < 64 ? 1 : 0); ++bb) {
        __syncthreads();
        xs[n] = xp[bb * 64 + n];
        __syncthreads();
        #pragma unroll
        for (int tt = 0; tt < (CHUNK < 64 ? CHUNK : 64); ++tt) s = a * s + bw * xs[tt];
    }
    carry[((size_t)b * NCH + c) * 64 + n] = s;
}

// ---------- in-place exclusive decay-scan of per-chunk carries ----------
__global__ __launch_bounds__(256)
void scan_carry(const float* __restrict__ nu_log, float* __restrict__ carry)
{
    const int b = blockIdx.x;
    const int tid = threadIdx.x;
    const int n = tid & 63, q = tid >> 6;
    const float ex = expf(nu_log[n]);
    const float aL = expf(-ex * (float)CHUNK);
    float* cp = carry + (size_t)b * NCH * 64 + n;
    __shared__ float part[4][64];

    const int SEG = NCH / 4;
    const int base = q * SEG;
    float p = 0.f;
    #pragma unroll 4
    for (int i = 0; i < SEG; ++i) {
        float v = cp[(size_t)(base + i) * 64];
        cp[(size_t)(base + i) * 64] = p;
        p = aL * p + v;
    }
    part[q][n] = p;
    __syncthreads();
    if (q > 0) {
        const float aLS = expf(-ex * (float)(CHUNK * SEG));
        float inc = 0.f;
        for (int qq = 0; qq < q; ++qq) inc = inc * aLS + part[qq][n];
        float qv = inc;
        #pragma unroll 4
        for (int i = 0; i < SEG; ++i) {
            cp[(size_t)(base + i) * 64] += qv;
            qv *= aL;
        }
    }
}

struct LPrep {
    const f16 *BmH, *BmL, *CmH, *CmL, *WlH;  // this layer (gamma folded into Bm)
    const float *av, *dvv, *bw, *dwin, *win; // this-layer scalars
    const f16 *BmHn, *BmLn;                  // next-layer Bm (gamma folded)
    const float *atabn;                      // next-layer decay table a^j
    const float *blin, *Wout;
};

// ---------- fused chunk kernel ----------
// 256 threads = 4 waves, each wave owns 16 rows (t = 16*w + 4*lq + r), CHUNK=64.
// LDS = 16K hpk + 1K swv + 1K red = 18432 B -> HW can pack 8 blocks/CU = 32 waves/CU.
// __launch_bounds__ kept at (256,4): round-1/2 lesson — min-waves=8 caps the unified
// VGPR+AGPR file at 64 regs and forces ~50 words/thread of scratch spill
// (+660 MB HBM/dispatch, dur 367->521 us regardless of occupancy). The (256,4)
// budget reproduces round-0 codegen (VGPR_Count=64, zero spill); occupancy then
// comes from LDS (8 blocks/CU), not from register starvation.
template<int IN_X, int OUT_FINAL>
__global__ __launch_bounds__(256, 4)
void lru_fused(const float* __restrict__ x, f16* __restrict__ ubuf,
               LPrep P, float* __restrict__ carry, float* __restrict__ out)
{
    const int blk = blockIdx.x;
    const int b = blk >> NCH_LOG, c = blk & (NCH - 1);
    const int t0 = c * CHUNK;
    const int tid = threadIdx.x;
    const int w = tid >> 6, lane = tid & 63;
    const int l15 = lane & 15, lq = lane >> 4;

    __shared__ float hpk[CHUNK * 64];   // 16 KB fp32: holds h_prev -> th -> staged o
    __shared__ float swv[4][64];
    __shared__ float red[4][64];

    f16* ug = ubuf + ((size_t)b * T_ + t0) * 64;
    const float* xg = x + (size_t)b * T_ + t0;

    // u A-frag (plain loads: ubuf is 128 MB and L3-resident; nt hints forced HBM)
    f16x8 ahu[2];
    if (!IN_X) {
        const f16* p = ug + (size_t)(16 * w + l15) * 64;
        ahu[0] = ldfrag(p + lq * 8);
        ahu[1] = ldfrag(p + 32 + lq * 8);
    }

    float av4[4];
    #pragma unroll
    for (int nt = 0; nt < 4; ++nt) av4[nt] = P.av[nt * 16 + l15];

    float xv[4];
    if (IN_X) {
        #pragma unroll
        for (int r = 0; r < 4; ++r) xv[r] = xg[16 * w + 4 * lq + r];
    }

    // ---- P1: Bu in registers (MFMA C-layout: row t=16w+lq*4+r, col n=nt*16+l15) ----
    f32x4 acc[4];
    if (IN_X) {
        #pragma unroll
        for (int nt = 0; nt < 4; ++nt) {
            float bwn = P.bw[nt * 16 + l15];
            #pragma unroll
            for (int r = 0; r < 4; ++r) acc[nt][r] = xv[r] * bwn;
        }
    } else {
        #pragma unroll
        for (int nt = 0; nt < 4; ++nt) {
            int n = nt * 16 + l15;
            f16x8 bh0 = ldfrag(P.BmH + n * 64 + lq * 8);
            f16x8 bh1 = ldfrag(P.BmH + n * 64 + 32 + lq * 8);
            f16x8 bl0 = ldfrag(P.BmL + n * 64 + lq * 8);
            f16x8 bl1 = ldfrag(P.BmL + n * 64 + 32 + lq * 8);
            f32x4 a4v = {0.f, 0.f, 0.f, 0.f};
            a4v = MFMA(ahu[0], bh0, a4v);
            a4v = MFMA(ahu[0], bl0, a4v);
            a4v = MFMA(ahu[1], bh1, a4v);
            a4v = MFMA(ahu[1], bl1, a4v);
            acc[nt] = a4v;
        }
    }

    // ---- P2: register scan with decayed shfl (per n, over own 16 rows) ----
    float Wb[4];
    #pragma unroll
    for (int nt = 0; nt < 4; ++nt) {
        float a = av4[nt], a2 = a * a, a4 = a2 * a2, a8 = a4 * a4;
        f32x4 xs = acc[nt];
        float L0 = xs[0];
        float L1 = a * L0 + xs[1];
        float L2 = a * L1 + xs[2];
        float Cv = a * L2 + xs[3];
        float u1 = __shfl_up(Cv, 16);
        float t1 = Cv + ((lq >= 1) ? a4 * u1 : 0.f);
        float u2 = __shfl_up(t1, 32);
        float Pv = t1 + ((lq >= 2) ? a8 * u2 : 0.f);
        float E = __shfl_up(Pv, 16);
        Wb[nt] = (lq == 0) ? 0.f : E;
        if (lq == 3) swv[w][nt * 16 + l15] = Pv;   // inclusive 16-row wave total
    }
    __syncthreads();                       // barrier 1

    // ---- inc + h_prev writes (fp32, own 16 rows) ----
    #pragma unroll
    for (int nt = 0; nt < 4; ++nt) {
        int n = nt * 16 + l15;
        float a = av4[nt], a2 = a * a, a4 = a2 * a2, a8 = a4 * a4, a16 = a8 * a8;
        float inc = carry[((size_t)b * NCH + c) * 64 + n];
        for (int ww = 0; ww < w; ++ww) inc = inc * a16 + swv[ww][n];
        float a4lq = 1.f;
        if (lq & 1) a4lq *= a4;
        if (lq & 2) a4lq *= a8;
        float s = Wb[nt] + a4lq * inc;
        #pragma unroll
        for (int r = 0; r < 4; ++r) {
            int t = 16 * w + 4 * lq + r;
            hpk[SWZ(t, n)] = s;           // h_{t-1}
            s = a * s + acc[nt][r];
        }
    }
    // no barrier: all subsequent hpk traffic is own-wave rows

    // ---- P3: y = C.h_prev + Dv*u, tanh -> th (fp32, overwrite h) ----
    {
        const int trow = 16 * w + l15, sw = (trow & 7) << 2;
        const float* hw = hpk + trow * 64;
        f16x8 ah[2], al[2];
        #pragma unroll
        for (int kk = 0; kk < 2; ++kk) {
            int kb = kk * 32 + lq * 8;
            float4 v0 = *(const float4*)(hw + (kb ^ sw));
            float4 v1 = *(const float4*)(hw + ((kb + 4) ^ sw));
            float vv[8] = {v0.x, v0.y, v0.z, v0.w, v1.x, v1.y, v1.z, v1.w};
            #pragma unroll
            for (int i = 0; i < 8; ++i) {
                f16 h = (f16)vv[i];
                ah[kk][i] = h;
                al[kk][i] = (f16)(vv[i] - (float)h);
            }
        }
        #pragma unroll
        for (int nt = 0; nt < 4; ++nt) {
            int n = nt * 16 + l15;
            f16x8 ch0 = ldfrag(P.CmH + n * 64 + lq * 8);
            f16x8 ch1 = ldfrag(P.CmH + n * 64 + 32 + lq * 8);
            f16x8 cl0 = ldfrag(P.CmL + n * 64 + lq * 8);
            f16x8 cl1 = ldfrag(P.CmL + n * 64 + 32 + lq * 8);
            f32x4 a4v = {0.f, 0.f, 0.f, 0.f};
            a4v = MFMA(ah[0], ch0, a4v);
            a4v = MFMA(al[0], ch0, a4v);
            a4v = MFMA(ah[0], cl0, a4v);
            a4v = MFMA(ah[1], ch1, a4v);
            a4v = MFMA(al[1], ch1, a4v);
            a4v = MFMA(ah[1], cl1, a4v);
            if (!IN_X) {
                float dv = P.dvv[n];
                f16 dh = (f16)dv, dl = (f16)(dv - (float)dh);
                f16x8 dfh, dfl;
                #pragma unroll
                for (int i2 = 0; i2 < 8; ++i2) { dfh[i2] = (f16)0.f; dfl[i2] = (f16)0.f; }
                int e = ((nt & 1) * 16 + l15) - lq * 8;
                if (e >= 0 && e < 8) { dfh[e] = dh; dfl[e] = dl; }
                a4v = MFMA(ahu[nt >> 1], dfh, a4v);
                a4v = MFMA(ahu[nt >> 1], dfl, a4v);
            }
            float dwin = IN_X ? P.dwin[n] : 0.f;
            #pragma unroll
            for (int r = 0; r < 4; ++r) {
                int t = 16 * w + lq * 4 + r;
                float y = a4v[r];
                if (IN_X) y += xv[r] * dwin;
                hpk[SWZ(t, n)] = y * rsqrtf(1.f + y * y);
            }
        }
    }

    // ---- P4: o = Wlin.th + blin + u; stage as f16 (low 32 words) or final reduce ----
    f16* stg = (f16*)hpk;
    {
        const int trow = 16 * w + l15, sw = (trow & 7) << 2;
        const float* hw = hpk + trow * 64;
        f16x8 t0f, t1f;
        #pragma unroll
        for (int kk = 0; kk < 2; ++kk) {
            int kb = kk * 32 + lq * 8;
            float4 v0 = *(const float4*)(hw + (kb ^ sw));
            float4 v1 = *(const float4*)(hw + ((kb + 4) ^ sw));
            float vv[8] = {v0.x, v0.y, v0.z, v0.w, v1.x, v1.y, v1.z, v1.w};
            #pragma unroll
            for (int i = 0; i < 8; ++i) {
                if (kk == 0) t0f[i] = (f16)vv[i]; else t1f[i] = (f16)vv[i];
            }
        }
        float val[4] = {0.f, 0.f, 0.f, 0.f};
        #pragma unroll
        for (int nt = 0; nt < 4; ++nt) {
            int n = nt * 16 + l15;
            f16x8 w0f = ldfrag(P.WlH + n * 64 + lq * 8);
            f16x8 w1f = ldfrag(P.WlH + n * 64 + 32 + lq * 8);
            f32x4 a4v = {0.f, 0.f, 0.f, 0.f};
            a4v = MFMA(t0f, w0f, a4v);
            a4v = MFMA(t1f, w1f, a4v);
            if (!IN_X) {
                f16x8 ifr;
                #pragma unroll
                for (int i2 = 0; i2 < 8; ++i2) ifr[i2] = (f16)0.f;
                int e = ((nt & 1) * 16 + l15) - lq * 8;
                if (e >= 0 && e < 8) ifr[e] = (f16)1.f;
                a4v = MFMA(ahu[nt >> 1], ifr, a4v);
            }
            float blj = P.blin[n];
            float wij = IN_X ? P.win[n] : 0.f;
            float woj = OUT_FINAL ? P.Wout[n] : 0.f;
            #pragma unroll
            for (int r = 0; r < 4; ++r) {
                int t = 16 * w + lq * 4 + r;
                float o = a4v[r] + blj;
                if (IN_X) o += xv[r] * wij;
                if (OUT_FINAL) {
                    val[r] += o * woj;
                } else {
                    int g = n >> 1;
                    int word = t * 64 + (((g & ~3) ^ ((t & 7) << 2)) | (g & 3));
                    stg[word * 2 + (n & 1)] = (f16)o;
                }
            }
        }
        if (OUT_FINAL) {
            #pragma unroll
            for (int r = 0; r < 4; ++r) {
                float p = val[r];
                p += __shfl_xor(p, 1);
                p += __shfl_xor(p, 2);
                p += __shfl_xor(p, 4);
                p += __shfl_xor(p, 8);
                if (l15 == 0) out[(size_t)b * T_ + t0 + 16 * w + lq * 4 + r] = p;
            }
        }
    }

    if (!OUT_FINAL) {
        // ---- coalesced store of own 16 rows (L3-cacheable for next dispatch) ----
        #pragma unroll
        for (int i = 0; i < 2; ++i) {
            int row = 16 * w + i * 8 + (lane >> 3);
            int gg = 4 * (lane & 7);
            int word = row * 64 + (gg ^ ((row & 7) << 2));
            u32x4 cv = *(const u32x4*)(hpk + word);
            *(u32x4*)(ug + (size_t)row * 64 + 8 * (lane & 7)) = cv;
        }

        // ---- next-layer raw-carry GEMM from staged tile ----
        float partial[4] = {0.f, 0.f, 0.f, 0.f};
        {
            const int arow = 16 * w + l15, msk = (arow & 7) << 2;
            U4F8 av0, av1;
            av0.u = *(const u32x4*)(hpk + arow * 64 + ((4 * lq) ^ msk));
            av1.u = *(const u32x4*)(hpk + arow * 64 + ((16 + 4 * lq) ^ msk));
            #pragma unroll
            for (int nt = 0; nt < 4; ++nt) {
                int n = nt * 16 + l15;
                f16x8 bh0 = ldfrag(P.BmHn + n * 64 + lq * 8);
                f16x8 bh1 = ldfrag(P.BmHn + n * 64 + 32 + lq * 8);
                f16x8 bl0 = ldfrag(P.BmLn + n * 64 + lq * 8);
                f16x8 bl1 = ldfrag(P.BmLn + n * 64 + 32 + lq * 8);
                f32x4 a4v = {0.f, 0.f, 0.f, 0.f};
                a4v = MFMA(av0.h, bh0, a4v);
                a4v = MFMA(av0.h, bl0, a4v);
                a4v = MFMA(av1.h, bh1, a4v);
                a4v = MFMA(av1.h, bl1, a4v);
                // decay weight a^(CHUNK-1-t), t = 16w+4lq+r
                float4 dp = *(const float4*)(P.atabn + n * 128 + (CHUNK - 4) - w * 16 - lq * 4);
                partial[nt] += a4v[0] * dp.w + a4v[1] * dp.z + a4v[2] * dp.y + a4v[3] * dp.x;
            }
        }
        #pragma unroll
        for (int nt = 0; nt < 4; ++nt) {
            float v = partial[nt];
            v += __shfl_xor(v, 16);
            v += __shfl_xor(v, 32);
            if (lq == 0) red[w][nt * 16 + l15] = v;
        }
        __syncthreads();                   // barrier 2
        if (w == 0)
            carry[((size_t)b * NCH + c) * 64 + lane] =
                red[0][lane] + red[1][lane] + red[2][lane] + red[3][lane];
    }
}

// ---------- host ----------
extern "C" void kernel_launch(void* const* d_in, const int* in_sizes, int n_in,
                              void* d_out, int out_size, void* d_ws, size_t ws_size,
                              hipStream_t stream)
{
    const float* x   = (const float*)d_in[0];
    const float* Win = (const float*)d_in[1];
    const float* nu  = (const float*)d_in[2];
    const float* ga  = (const float*)d_in[3];
    const float* Bm  = (const float*)d_in[4];
    const float* Cm  = (const float*)d_in[5];
    const float* Dv  = (const float*)d_in[6];
    const float* Wl  = (const float*)d_in[7];
    const float* bl  = (const float*)d_in[8];
    const float* Wo  = (const float*)d_in[9];
    float* out = (float*)d_out;

    char* p = (char*)d_ws;
    f16* ubuf = (f16*)p;            p += (size_t)B_ * T_ * 64 * sizeof(f16);
    float* carry = (float*)p;       p += (size_t)B_ * NCH * 64 * sizeof(float);
    f16* wBmH = (f16*)p;            p += 4 * 4096 * sizeof(f16);
    f16* wBmL = (f16*)p;            p += 4 * 4096 * sizeof(f16);
    f16* wCmH = (f16*)p;            p += 4 * 4096 * sizeof(f16);
    f16* wCmL = (f16*)p;            p += 4 * 4096 * sizeof(f16);
    f16* wWlH = (f16*)p;            p += 4 * 4096 * sizeof(f16);
    float* atab = (float*)p;        p += 4 * 8192 * sizeof(float);
    float* sc = (float*)p;          p += 4 * 320 * sizeof(float);

    dim3 grid(B_ * NCH), blk256(256), blk64(64), gscan(B_);

    prep<<<1, blk256, 0, stream>>>(Win, nu, ga, Bm, Cm, Dv, Wl,
                                   wBmH, wBmL, wCmH, wCmL, wWlH, atab, sc);
    carry_x<<<grid, blk64, 0, stream>>>(x, sc, carry);

    for (int l = 0; l < DEPTH_; ++l) {
        int ln = (l + 1 < DEPTH_) ? l + 1 : l;
        scan_carry<<<gscan, blk256, 0, stream>>>(nu + l * 64, carry);
        LPrep Pr;
        Pr.BmH = wBmH + l * 4096;  Pr.BmL = wBmL + l * 4096;
        Pr.CmH = wCmH + l * 4096;  Pr.CmL = wCmL + l * 4096;
        Pr.WlH = wWlH + l * 4096;
        Pr.av = sc + l * 320;       Pr.dvv = sc + l * 320 + 64;
        Pr.bw = sc + l * 320 + 128; Pr.dwin = sc + l * 320 + 192;
        Pr.win = sc + l * 320 + 256;
        Pr.BmHn = wBmH + ln * 4096; Pr.BmLn = wBmL + ln * 4096;
        Pr.atabn = atab + ln * 8192;
        Pr.blin = bl + l * 64; Pr.Wout = Wo;
        if (l == 0)
            lru_fused<1, 0><<<grid, blk256, 0, stream>>>(x, ubuf, Pr, carry, out);
        else if (l == DEPTH_ - 1)
            lru_fused<0, 1><<<grid, blk256, 0, stream>>>(x, ubuf, Pr, carry, out);
        else
            lru_fused<0, 0><<<grid, blk256, 0, stream>>>(x, ubuf, Pr, carry, out);
    }
}

// Round 4
// 1538.648 us; speedup vs baseline: 1.2572x; 1.1880x over previous
//
#include <hip/hip_runtime.h>

#define B_ 16
#define T_ 65536
#define H_ 64
#define DEPTH_ 4
#define CHUNK 128
#define NCH (T_ / CHUNK)   // 512 chunks per sequence
#define NCH_LOG 9

typedef _Float16 f16;
typedef f16 f16x8 __attribute__((ext_vector_type(8)));
typedef float f32x4 __attribute__((ext_vector_type(4)));
typedef unsigned u32x4 __attribute__((ext_vector_type(4)));

#define MFMA(a, b, c) __builtin_amdgcn_mfma_f32_16x16x32_f16(a, b, c, 0, 0, 0)
// swizzled word index into hpk: row t (0..127), word k (0..63)
#define SWZ(t, k) ((t) * 64 + ((k) ^ (((t) & 7) << 2)))

union U4F8 { u32x4 u; f16x8 h; };

__device__ __forceinline__ f16x8 ldfrag(const f16* p) { return *(const f16x8*)p; }

// ---------- prep: pack weights to f16 hi/lo, decay tables, scalars ----------
// sc per layer (stride 320 floats): [0]=a, [64]=Dv, [128]=bw(=g*Bm.Win), [192]=Dv*Win, [256]=Win
__global__ __launch_bounds__(256)
void prep(const float* __restrict__ Win, const float* __restrict__ nu,
          const float* __restrict__ ga, const float* __restrict__ Bm,
          const float* __restrict__ Cm, const float* __restrict__ Dv,
          const float* __restrict__ Wl,
          f16* __restrict__ BmH, f16* __restrict__ BmL,
          f16* __restrict__ CmH, f16* __restrict__ CmL,
          f16* __restrict__ WlH, float* __restrict__ atab, float* __restrict__ sc)
{
    const int tid = threadIdx.x;
    for (int l = 0; l < DEPTH_; ++l) {
        for (int idx = tid; idx < 4096; idx += 256) {
            int n = idx >> 6;
            float g = expf(ga[l * 64 + n]);
            float v = Bm[l * 4096 + idx] * g;
            f16 h = (f16)v;
            BmH[l * 4096 + idx] = h;
            BmL[l * 4096 + idx] = (f16)(v - (float)h);
            float cv = Cm[l * 4096 + idx];
            h = (f16)cv;
            CmH[l * 4096 + idx] = h;
            CmL[l * 4096 + idx] = (f16)(cv - (float)h);
            WlH[l * 4096 + idx] = (f16)Wl[l * 4096 + idx];
        }
        if (tid < 64) {
            int n = tid;
            float ex = expf(nu[l * 64 + n]);
            float a = expf(-ex);
            float g = expf(ga[l * 64 + n]);
            sc[l * 320 + n] = a;
            sc[l * 320 + 64 + n] = Dv[l * 64 + n];
            float bw = 0.f;
            for (int h2 = 0; h2 < 64; ++h2) bw += Bm[l * 4096 + n * 64 + h2] * Win[h2];
            sc[l * 320 + 128 + n] = bw * g;
            sc[l * 320 + 192 + n] = Dv[l * 64 + n] * Win[n];
            sc[l * 320 + 256 + n] = Win[n];
        }
        for (int idx = tid; idx < 8192; idx += 256) {
            int n = idx >> 7, j = idx & 127;
            float ex = expf(nu[l * 64 + n]);
            atab[l * 8192 + idx] = expf(-ex * (float)j);
        }
    }
}

// ---------- raw carry for layer 0 (u_t = x_t*Win, rank-1) ----------
__global__ __launch_bounds__(64)
void carry_x(const float* __restrict__ x, const float* __restrict__ sc0,
             float* __restrict__ carry)
{
    const int blk = blockIdx.x;
    const int b = blk >> NCH_LOG, c = blk & (NCH - 1);
    const int n = threadIdx.x;
    const float a  = sc0[n];
    const float bw = sc0[128 + n];
    __shared__ float xs[64];
    const float* xp = x + (size_t)b * T_ + c * CHUNK;
    float s = 0.f;
    for (int bb = 0; bb < CHUNK / 64; ++bb) {
        __syncthreads();
        xs[n] = xp[bb * 64 + n];
        __syncthreads();
        #pragma unroll
        for (int tt = 0; tt < 64; ++tt) s = a * s + bw * xs[tt];
    }
    carry[((size_t)b * NCH + c) * 64 + n] = s;
}

// ---------- in-place exclusive decay-scan of per-chunk carries ----------
// Also zeroes carry_next so the fused kernel can atomicAdd next-layer raw carries.
__global__ __launch_bounds__(256)
void scan_carry(const float* __restrict__ nu_log, float* __restrict__ carry,
                float* __restrict__ carry_next)
{
    const int b = blockIdx.x;
    const int tid = threadIdx.x;
    const int n = tid & 63, q = tid >> 6;
    const float ex = expf(nu_log[n]);
    const float aL = expf(-ex * (float)CHUNK);
    float* cp = carry + (size_t)b * NCH * 64 + n;
    float* zp = carry_next + (size_t)b * NCH * 64 + n;
    __shared__ float part[4][64];

    const int SEG = NCH / 4;
    const int base = q * SEG;
    float p = 0.f;
    #pragma unroll 4
    for (int i = 0; i < SEG; ++i) {
        float v = cp[(size_t)(base + i) * 64];
        cp[(size_t)(base + i) * 64] = p;
        zp[(size_t)(base + i) * 64] = 0.f;
        p = aL * p + v;
    }
    part[q][n] = p;
    __syncthreads();
    if (q > 0) {
        const float aLS = expf(-ex * (float)(CHUNK * SEG));
        float inc = 0.f;
        for (int qq = 0; qq < q; ++qq) inc = inc * aLS + part[qq][n];
        float qv = inc;
        #pragma unroll 4
        for (int i = 0; i < SEG; ++i) {
            cp[(size_t)(base + i) * 64] += qv;
            qv *= aL;
        }
    }
}

struct LPrep {
    const f16 *BmH, *BmL, *CmH, *CmL, *WlH;  // this layer (gamma folded into Bm)
    const float *av, *dvv, *bw, *dwin, *win; // this-layer scalars
    const f16 *BmHn, *BmLn;                  // next-layer Bm (gamma folded)
    const float *atabn;                      // next-layer decay table a^j
    const float *blin, *Wout;
};

// ---------- fused chunk kernel ----------
// CHUNK=128, 4 waves x 32 rows. LDS = hpk only = 32768 B exactly -> 5 blocks/CU.
// Register theory (r0-r3 evidence): reported VGPR_Count is arch-VGPRs only; the
// launch-bounds budget is VGPR+accum total. (256,4)=128 total -> 4 waves/SIMD
// (45% occ, r0/r3); (512,8)=64 total -> mass spill (r1/r2). Here: (256,5) = ~102
// total budget, and the kernel footprint is trimmed to fit by (a) killing the
// Dv/identity diagonal-MFMA tricks (ahu dies after P1, -16 persistent VGPRs,
// -24 MFMAs, -~240 VALU frag-construction ops) in favor of direct C-layout u
// reloads (L2-warm), (b) swv moved to global scratch, (c) red + barrier 2
// replaced by atomicAdd into a pre-zeroed ping-pong carry buffer.
template<int IN_X, int OUT_FINAL>
__global__ __launch_bounds__(256, 5)
void lru_fused(const float* __restrict__ x, f16* __restrict__ ubuf,
               LPrep P, const float* __restrict__ carry,
               float* __restrict__ carry_out, float* __restrict__ swv_g,
               float* __restrict__ out)
{
    const int blk = blockIdx.x;
    const int b = blk >> NCH_LOG, c = blk & (NCH - 1);
    const int t0 = c * CHUNK;
    const int tid = threadIdx.x;
    const int w = tid >> 6, lane = tid & 63;
    const int l15 = lane & 15, lq = lane >> 4;

    __shared__ float hpk[CHUNK * 64];   // 32 KB exactly: h_prev -> th -> staged o

    f16* ug = ubuf + ((size_t)b * T_ + t0) * 64;
    const float* xg = x + (size_t)b * T_ + t0;
    float* swvg = swv_g + (size_t)blk * 192;   // [3 waves][64] cross-wave totals

    // u A-frags: only needed for P1 now (liveness ends there)
    f16x8 ahu[2][2];
    if (!IN_X) {
        #pragma unroll
        for (int tt = 0; tt < 2; ++tt) {
            const f16* p = ug + (size_t)((2 * w + tt) * 16 + l15) * 64;
            ahu[tt][0] = ldfrag(p + lq * 8);
            ahu[tt][1] = ldfrag(p + 32 + lq * 8);
        }
    }

    float av4[4];
    #pragma unroll
    for (int nt = 0; nt < 4; ++nt) av4[nt] = P.av[nt * 16 + l15];

    float xv[2][4];
    if (IN_X) {
        #pragma unroll
        for (int tt = 0; tt < 2; ++tt)
            #pragma unroll
            for (int r = 0; r < 4; ++r)
                xv[tt][r] = xg[32 * w + 16 * tt + 4 * lq + r];
    }

    // ---- P1: Bu in registers (MFMA C-layout: row t=tb*16+lq*4+r, col n=nt*16+l15) ----
    f32x4 acc[4][2];
    if (IN_X) {
        #pragma unroll
        for (int nt = 0; nt < 4; ++nt) {
            float bwn = P.bw[nt * 16 + l15];
            #pragma unroll
            for (int tt = 0; tt < 2; ++tt)
                #pragma unroll
                for (int r = 0; r < 4; ++r) acc[nt][tt][r] = xv[tt][r] * bwn;
        }
    } else {
        #pragma unroll
        for (int nt = 0; nt < 4; ++nt) {
            int n = nt * 16 + l15;
            f16x8 bh0 = ldfrag(P.BmH + n * 64 + lq * 8);
            f16x8 bh1 = ldfrag(P.BmH + n * 64 + 32 + lq * 8);
            f16x8 bl0 = ldfrag(P.BmL + n * 64 + lq * 8);
            f16x8 bl1 = ldfrag(P.BmL + n * 64 + 32 + lq * 8);
            #pragma unroll
            for (int tt = 0; tt < 2; ++tt) {
                f32x4 a4v = {0.f, 0.f, 0.f, 0.f};
                a4v = MFMA(ahu[tt][0], bh0, a4v);
                a4v = MFMA(ahu[tt][0], bl0, a4v);
                a4v = MFMA(ahu[tt][1], bh1, a4v);
                a4v = MFMA(ahu[tt][1], bl1, a4v);
                acc[nt][tt] = a4v;
            }
        }
    }

    // ---- P2: register scan with decayed shfl (per n, over t) ----
    float Wb[4][2];
    #pragma unroll
    for (int nt = 0; nt < 4; ++nt) {
        float a = av4[nt], a2 = a * a, a4 = a2 * a2, a8 = a4 * a4, a16 = a8 * a8;
        float P0incl = 0.f;
        #pragma unroll
        for (int tt = 0; tt < 2; ++tt) {
            f32x4 xs = acc[nt][tt];
            float L0 = xs[0];
            float L1 = a * L0 + xs[1];
            float L2 = a * L1 + xs[2];
            float Cv = a * L2 + xs[3];
            float u1 = __shfl_up(Cv, 16);
            float t1 = Cv + ((lq >= 1) ? a4 * u1 : 0.f);
            float u2 = __shfl_up(t1, 32);
            float Pv = t1 + ((lq >= 2) ? a8 * u2 : 0.f);
            float E = __shfl_up(Pv, 16);
            E = (lq == 0) ? 0.f : E;
            if (tt == 0) { Wb[nt][0] = E; P0incl = Pv; }
            else {
                float B0 = __shfl(P0incl, 48 + l15);
                float a4lq = 1.f;
                if (lq & 1) a4lq *= a4;
                if (lq & 2) a4lq *= a8;
                Wb[nt][1] = E + a4lq * B0;
                if (lq == 3 && w < 3)
                    swvg[w * 64 + nt * 16 + l15] = Pv + a16 * B0;  // wave 32-row total
            }
        }
    }
    __syncthreads();                       // barrier 1 (drains the swvg stores too)

    // ---- inc + h_prev writes (fp32, own rows) ----
    #pragma unroll
    for (int nt = 0; nt < 4; ++nt) {
        int n = nt * 16 + l15;
        float a = av4[nt], a2 = a * a, a4 = a2 * a2, a8 = a4 * a4, a16 = a8 * a8, a32 = a16 * a16;
        // independent loads, wave-uniform combine (no serial load chain)
        float s0 = swvg[n], s1 = swvg[64 + n], s2 = swvg[128 + n];
        float inc = carry[((size_t)b * NCH + c) * 64 + n];
        if (w == 1)      inc = inc * a32 + s0;
        else if (w == 2) inc = (inc * a32 + s0) * a32 + s1;
        else if (w == 3) inc = ((inc * a32 + s0) * a32 + s1) * a32 + s2;
        float a4lq = 1.f;
        if (lq & 1) a4lq *= a4;
        if (lq & 2) a4lq *= a8;
        #pragma unroll
        for (int tt = 0; tt < 2; ++tt) {
            float Z = Wb[nt][tt] + a4lq * (tt ? a16 : 1.f) * inc;
            float s = Z;
            #pragma unroll
            for (int r = 0; r < 4; ++r) {
                int t = 32 * w + 16 * tt + 4 * lq + r;
                hpk[SWZ(t, n)] = s;           // h_{t-1}
                s = a * s + acc[nt][tt][r];
            }
        }
    }
    // no barrier: all subsequent hpk traffic is own-wave rows

    // ---- P3: y = C.h_prev + Dv*u, tanh -> th (fp32, overwrite h) ----
    #pragma unroll
    for (int tt = 0; tt < 2; ++tt) {
        int tb = 2 * w + tt, trow = tb * 16 + l15, sw = (trow & 7) << 2;
        const float* hw = hpk + trow * 64;
        f16x8 ah[2], al[2];
        #pragma unroll
        for (int kk = 0; kk < 2; ++kk) {
            int kb = kk * 32 + lq * 8;
            float4 v0 = *(const float4*)(hw + (kb ^ sw));
            float4 v1 = *(const float4*)(hw + ((kb + 4) ^ sw));
            float vv[8] = {v0.x, v0.y, v0.z, v0.w, v1.x, v1.y, v1.z, v1.w};
            #pragma unroll
            for (int i = 0; i < 8; ++i) {
                f16 h = (f16)vv[i];
                ah[kk][i] = h;
                al[kk][i] = (f16)(vv[i] - (float)h);
            }
        }
        #pragma unroll
        for (int nt = 0; nt < 4; ++nt) {
            int n = nt * 16 + l15;
            f16x8 ch0 = ldfrag(P.CmH + n * 64 + lq * 8);
            f16x8 ch1 = ldfrag(P.CmH + n * 64 + 32 + lq * 8);
            f16x8 cl0 = ldfrag(P.CmL + n * 64 + lq * 8);
            f16x8 cl1 = ldfrag(P.CmL + n * 64 + 32 + lq * 8);
            f32x4 a4v = {0.f, 0.f, 0.f, 0.f};
            a4v = MFMA(ah[0], ch0, a4v);
            a4v = MFMA(al[0], ch0, a4v);
            a4v = MFMA(ah[0], cl0, a4v);
            a4v = MFMA(ah[1], ch1, a4v);
            a4v = MFMA(al[1], ch1, a4v);
            a4v = MFMA(ah[1], cl1, a4v);
            float dwin = IN_X ? P.dwin[n] : 0.f;
            float dv   = IN_X ? 0.f : P.dvv[n];
            #pragma unroll
            for (int r = 0; r < 4; ++r) {
                int t = tb * 16 + lq * 4 + r;
                float y = a4v[r];
                if (IN_X) y += xv[tt][r] * dwin;
                else      y += dv * (float)ug[(size_t)t * 64 + n];  // fp32 Dv*u, L2-warm
                hpk[SWZ(t, n)] = y * rsqrtf(1.f + y * y);
            }
        }
    }

    // ---- P4: o = Wlin.th + blin + u; stage as f16 or final reduce ----
    f16* stg = (f16*)hpk;
    #pragma unroll
    for (int tt = 0; tt < 2; ++tt) {
        int tb = 2 * w + tt, trow = tb * 16 + l15, sw = (trow & 7) << 2;
        const float* hw = hpk + trow * 64;
        f16x8 t0f, t1f;
        #pragma unroll
        for (int kk = 0; kk < 2; ++kk) {
            int kb = kk * 32 + lq * 8;
            float4 v0 = *(const float4*)(hw + (kb ^ sw));
            float4 v1 = *(const float4*)(hw + ((kb + 4) ^ sw));
            float vv[8] = {v0.x, v0.y, v0.z, v0.w, v1.x, v1.y, v1.z, v1.w};
            #pragma unroll
            for (int i = 0; i < 8; ++i) {
                if (kk == 0) t0f[i] = (f16)vv[i]; else t1f[i] = (f16)vv[i];
            }
        }
        float val[4] = {0.f, 0.f, 0.f, 0.f};
        #pragma unroll
        for (int nt = 0; nt < 4; ++nt) {
            int n = nt * 16 + l15;
            f16x8 w0f = ldfrag(P.WlH + n * 64 + lq * 8);
            f16x8 w1f = ldfrag(P.WlH + n * 64 + 32 + lq * 8);
            f32x4 a4v = {0.f, 0.f, 0.f, 0.f};
            a4v = MFMA(t0f, w0f, a4v);
            a4v = MFMA(t1f, w1f, a4v);
            float blj = P.blin[n];
            float wij = IN_X ? P.win[n] : 0.f;
            float woj = OUT_FINAL ? P.Wout[n] : 0.f;
            #pragma unroll
            for (int r = 0; r < 4; ++r) {
                int t = tb * 16 + lq * 4 + r;
                float o = a4v[r] + blj;
                if (IN_X) o += xv[tt][r] * wij;
                else      o += (float)ug[(size_t)t * 64 + n];   // residual +u, L2-warm
                if (OUT_FINAL) {
                    val[r] += o * woj;
                } else {
                    int g = n >> 1;
                    int word = t * 64 + (((g & ~3) ^ ((t & 7) << 2)) | (g & 3));
                    stg[word * 2 + (n & 1)] = (f16)o;
                }
            }
        }
        if (OUT_FINAL) {
            #pragma unroll
            for (int r = 0; r < 4; ++r) {
                float p = val[r];
                p += __shfl_xor(p, 1);
                p += __shfl_xor(p, 2);
                p += __shfl_xor(p, 4);
                p += __shfl_xor(p, 8);
                if (l15 == 0) out[(size_t)b * T_ + t0 + tb * 16 + lq * 4 + r] = p;
            }
        }
    }

    if (!OUT_FINAL) {
        // ---- coalesced store of own 32 rows ----
        #pragma unroll
        for (int i = 0; i < 4; ++i) {
            int row = 32 * w + i * 8 + (lane >> 3);
            int gg = 4 * (lane & 7);
            int word = row * 64 + (gg ^ ((row & 7) << 2));
            u32x4 cv = *(const u32x4*)(hpk + word);
            *(u32x4*)(ug + (size_t)row * 64 + 8 * (lane & 7)) = cv;
        }

        // ---- next-layer raw-carry GEMM from staged tile ----
        float partial[4] = {0.f, 0.f, 0.f, 0.f};
        #pragma unroll
        for (int tt = 0; tt < 2; ++tt) {
            int tb = 2 * w + tt, arow = tb * 16 + l15, msk = (arow & 7) << 2;
            U4F8 av0, av1;
            av0.u = *(const u32x4*)(hpk + arow * 64 + ((4 * lq) ^ msk));
            av1.u = *(const u32x4*)(hpk + arow * 64 + ((16 + 4 * lq) ^ msk));
            #pragma unroll
            for (int nt = 0; nt < 4; ++nt) {
                int n = nt * 16 + l15;
                f16x8 bh0 = ldfrag(P.BmHn + n * 64 + lq * 8);
                f16x8 bh1 = ldfrag(P.BmHn + n * 64 + 32 + lq * 8);
                f16x8 bl0 = ldfrag(P.BmLn + n * 64 + lq * 8);
                f16x8 bl1 = ldfrag(P.BmLn + n * 64 + 32 + lq * 8);
                f32x4 a4v = {0.f, 0.f, 0.f, 0.f};
                a4v = MFMA(av0.h, bh0, a4v);
                a4v = MFMA(av0.h, bl0, a4v);
                a4v = MFMA(av1.h, bh1, a4v);
                a4v = MFMA(av1.h, bl1, a4v);
                float4 dp = *(const float4*)(P.atabn + n * 128 + 124 - tb * 16 - lq * 4);
                partial[nt] += a4v[0] * dp.w + a4v[1] * dp.z + a4v[2] * dp.y + a4v[3] * dp.x;
            }
        }
        // cross-wave reduce via device atomics into pre-zeroed carry_out
        // (no red LDS, no barrier 2; carry_out != carry so no intra-block ordering needed)
        #pragma unroll
        for (int nt = 0; nt < 4; ++nt) {
            float v = partial[nt];
            v += __shfl_xor(v, 16);
            v += __shfl_xor(v, 32);
            if (lq == 0)
                atomicAdd(&carry_out[((size_t)b * NCH + c) * 64 + nt * 16 + l15], v);
        }
    }
}

// ---------- host ----------
extern "C" void kernel_launch(void* const* d_in, const int* in_sizes, int n_in,
                              void* d_out, int out_size, void* d_ws, size_t ws_size,
                              hipStream_t stream)
{
    const float* x   = (const float*)d_in[0];
    const float* Win = (const float*)d_in[1];
    const float* nu  = (const float*)d_in[2];
    const float* ga  = (const float*)d_in[3];
    const float* Bm  = (const float*)d_in[4];
    const float* Cm  = (const float*)d_in[5];
    const float* Dv  = (const float*)d_in[6];
    const float* Wl  = (const float*)d_in[7];
    const float* bl  = (const float*)d_in[8];
    const float* Wo  = (const float*)d_in[9];
    float* out = (float*)d_out;

    char* p = (char*)d_ws;
    f16* ubuf = (f16*)p;            p += (size_t)B_ * T_ * 64 * sizeof(f16);
    float* carryA = (float*)p;      p += (size_t)B_ * NCH * 64 * sizeof(float);
    float* carryB = (float*)p;      p += (size_t)B_ * NCH * 64 * sizeof(float);
    float* swvg = (float*)p;        p += (size_t)B_ * NCH * 192 * sizeof(float);
    f16* wBmH = (f16*)p;            p += 4 * 4096 * sizeof(f16);
    f16* wBmL = (f16*)p;            p += 4 * 4096 * sizeof(f16);
    f16* wCmH = (f16*)p;            p += 4 * 4096 * sizeof(f16);
    f16* wCmL = (f16*)p;            p += 4 * 4096 * sizeof(f16);
    f16* wWlH = (f16*)p;            p += 4 * 4096 * sizeof(f16);
    float* atab = (float*)p;        p += 4 * 8192 * sizeof(float);
    float* sc = (float*)p;          p += 4 * 320 * sizeof(float);

    dim3 grid(B_ * NCH), blk256(256), blk64(64), gscan(B_);

    prep<<<1, blk256, 0, stream>>>(Win, nu, ga, Bm, Cm, Dv, Wl,
                                   wBmH, wBmL, wCmH, wCmL, wWlH, atab, sc);
    carry_x<<<grid, blk64, 0, stream>>>(x, sc, carryA);

    float* cR = carryA;
    float* cW = carryB;
    for (int l = 0; l < DEPTH_; ++l) {
        int ln = (l + 1 < DEPTH_) ? l + 1 : l;
        // scans cR in place (raw -> exclusive-scanned); zeroes cW for atomicAdds
        scan_carry<<<gscan, blk256, 0, stream>>>(nu + l * 64, cR, cW);
        LPrep Pr;
        Pr.BmH = wBmH + l * 4096;  Pr.BmL = wBmL + l * 4096;
        Pr.CmH = wCmH + l * 4096;  Pr.CmL = wCmL + l * 4096;
        Pr.WlH = wWlH + l * 4096;
        Pr.av = sc + l * 320;       Pr.dvv = sc + l * 320 + 64;
        Pr.bw = sc + l * 320 + 128; Pr.dwin = sc + l * 320 + 192;
        Pr.win = sc + l * 320 + 256;
        Pr.BmHn = wBmH + ln * 4096; Pr.BmLn = wBmL + ln * 4096;
        Pr.atabn = atab + ln * 8192;
        Pr.blin = bl + l * 64; Pr.Wout = Wo;
        if (l == 0)
            lru_fused<1, 0><<<grid, blk256, 0, stream>>>(x, ubuf, Pr, cR, cW, swvg, out);
        else if (l == DEPTH_ - 1)
            lru_fused<0, 1><<<grid, blk256, 0, stream>>>(x, ubuf, Pr, cR, cW, swvg, out);
        else
            lru_fused<0, 0><<<grid, blk256, 0, stream>>>(x, ubuf, Pr, cR, cW, swvg, out);
        float* tmp = cR; cR = cW; cW = tmp;
    }
}